// Round 2
// baseline (1817.210 us; speedup 1.0000x reference)
//
#include <hip/hip_runtime.h>
#include <math.h>
#include <stddef.h>

// ---------------- problem constants ----------------
constexpr int T_ = 64;
constexpr int H_ = 1024;
constexpr int W_ = 1024;
constexpr int N_ = H_ * W_;
// int((1.0-0.15)*(N-1)) and int(0.3*(N-1)) with python double semantics
constexpr unsigned RANK_G = 891288;   // 85th pct index of gm (ascending, 0-based)
constexpr unsigned RANK_B = 314572;   // 30th pct index of |f|

constexpr int ROWS_PER_BLOCK = 32;
constexpr int BLOCKS_PER_FRAME = H_ / ROWS_PER_BLOCK; // 32

// sampling: 16 rows/frame = 16384 samples; N/NS = 64
constexpr int SROWS = 16;
constexpr int NS = SROWS * W_;              // 16384
constexpr int SHB = 8192;                   // sample hist buckets (u>>18)
constexpr int MARGIN = 320;                 // sample-rank margin (~6 sigma)
constexpr unsigned RS_G = RANK_G / 64;      // 13926
constexpr unsigned RS_B = RANK_B / 64;      // 4915
constexpr unsigned CAP = 98304;             // candidate cap per (q,frame); expect ~60k

// ---------------- workspace layout ----------------
struct WS {
  unsigned lo[2][T_], hi[2][T_];       // value bracket (bit patterns)
  unsigned cand_cnt[2][T_];
  unsigned cnt_below[2][T_];           // exact #{u < lo}
  float    thr[2][T_];
  double   acc[T_][4];                 // cnt, sum_gm, sum_gm*x, sum_gm*y
  unsigned cand[2][T_][CAP];           // NOT memset (50 MB)
};

// Shared gm computation so every pass rounds identically.
__device__ __forceinline__ float gm_at(float cur, float right, float down,
                                       int col, int row) {
  float gx = (col < W_ - 1) ? (right - cur) : 0.0f;
  float gy = (row < H_ - 1) ? (down - cur) : 0.0f;
  return sqrtf(gx * gx + gy * gy);
}

// ---------------- pass 0: sampled bracket estimation ----------------
__global__ __launch_bounds__(256) void sample_kernel(const float* __restrict__ frames,
                                                     WS* ws) {
  const int t = blockIdx.x;
  __shared__ unsigned hist[2][SHB];    // 64 KB
  for (int i = threadIdx.x; i < 2 * SHB; i += 256) (&hist[0][0])[i] = 0;
  __syncthreads();
  const float* f = frames + (size_t)t * N_;
  const int tx = threadIdx.x, c = tx * 4;
  for (int r = 0; r < SROWS; ++r) {
    const int h = r * 64 + 32;                 // rows 32..992, h+1 always valid
    const float* row = f + (size_t)h * W_;
    float4 a = *(const float4*)(row + c);
    float an = (c + 4 < W_) ? row[c + 4] : 0.0f;
    float4 b = *(const float4*)(row + W_ + c);
    float xs[5] = {a.x, a.y, a.z, a.w, an};
    float ys[4] = {b.x, b.y, b.z, b.w};
#pragma unroll
    for (int j = 0; j < 4; ++j) {
      float gm = gm_at(xs[j], xs[j + 1], ys[j], c + j, h);
      float bz = fabsf(xs[j]);
      atomicAdd(&hist[0][__float_as_uint(gm) >> 18], 1u);
      atomicAdd(&hist[1][__float_as_uint(bz) >> 18], 1u);
    }
  }
  __syncthreads();
  __shared__ unsigned partial[256], chunk_before[256];
  for (int q = 0; q < 2; ++q) {
    unsigned s = 0;
    for (int j = 0; j < SHB / 256; ++j) s += hist[q][tx * (SHB / 256) + j];
    partial[tx] = s;
    __syncthreads();
    if (tx == 0) {
      unsigned cum = 0;
      for (int i = 0; i < 256; ++i) { chunk_before[i] = cum; cum += partial[i]; }
    }
    __syncthreads();
    const int rs = (q == 0) ? (int)RS_G : (int)RS_B;
    for (int e = 0; e < 2; ++e) {
      int k = (e == 0) ? rs - MARGIN : rs + MARGIN;
      if (k < 0) k = 0;
      if (k > NS - 1) k = NS - 1;
      unsigned cb = chunk_before[tx];
      if ((unsigned)k >= cb && (unsigned)k < cb + partial[tx]) {  // one thread
        unsigned rem = (unsigned)k - cb, cum = 0;
        for (int j = 0; j < SHB / 256; ++j) {
          unsigned hv = hist[q][tx * (SHB / 256) + j];
          if (rem < cum + hv) {
            unsigned bucket = tx * (SHB / 256) + j;
            if (e == 0) ws->lo[q][t] = bucket << 18;
            else        ws->hi[q][t] = (bucket + 1) << 18;
            break;
          }
          cum += hv;
        }
      }
      __syncthreads();
    }
    __syncthreads();
  }
}

// ---------------- pass 1: exact count-below + candidate compaction ----------------
__global__ __launch_bounds__(256) void count_compact_kernel(const float* __restrict__ frames,
                                                            WS* ws) {
  const int t = blockIdx.y, r0 = blockIdx.x * ROWS_PER_BLOCK;
  const unsigned lg = ws->lo[0][t], hg = ws->hi[0][t];
  const unsigned lb = ws->lo[1][t], hb = ws->hi[1][t];
  unsigned* __restrict__ candg = ws->cand[0][t];
  unsigned* __restrict__ candb = ws->cand[1][t];
  const float* f = frames + (size_t)t * N_;
  const int tx = threadIdx.x, c = tx * 4, lane = tx & 63;
  unsigned cbg = 0, cbb = 0;

  for (int r = 0; r < ROWS_PER_BLOCK; ++r) {
    const int h = r0 + r;
    const float* row = f + (size_t)h * W_;
    float4 a = *(const float4*)(row + c);
    float an = (c + 4 < W_) ? row[c + 4] : 0.0f;
    float4 b;
    if (h + 1 < H_) b = *(const float4*)(row + W_ + c);
    else            b = a;                        // forces gy = 0
    float xs[5] = {a.x, a.y, a.z, a.w, an};
    float ys[4] = {b.x, b.y, b.z, b.w};
    unsigned ug[4], ub[4], mg = 0, mb = 0, ng = 0, nb = 0;
#pragma unroll
    for (int j = 0; j < 4; ++j) {
      float gm = gm_at(xs[j], xs[j + 1], ys[j], c + j, h);
      float bz = fabsf(xs[j]);
      ug[j] = __float_as_uint(gm);
      ub[j] = __float_as_uint(bz);
      cbg += (ug[j] < lg);
      cbb += (ub[j] < lb);
      if (ug[j] >= lg && ug[j] < hg) { mg |= 1u << j; ng++; }
      if (ub[j] >= lb && ub[j] < hb) { mb |= 1u << j; nb++; }
    }
    // wave-aggregated append, one global atomic per wave per row per quantity
    {
      unsigned x = ng;
      for (int d = 1; d < 64; d <<= 1) { unsigned y = __shfl_up(x, d, 64); if (lane >= d) x += y; }
      unsigned total = __shfl(x, 63, 64);
      if (total) {
        unsigned base = 0;
        if (lane == 63) base = atomicAdd(&ws->cand_cnt[0][t], total);
        base = __shfl(base, 63, 64);
        unsigned off = base + x - ng;
#pragma unroll
        for (int j = 0; j < 4; ++j)
          if ((mg >> j) & 1u) { if (off < CAP) candg[off] = ug[j]; off++; }
      }
    }
    {
      unsigned x = nb;
      for (int d = 1; d < 64; d <<= 1) { unsigned y = __shfl_up(x, d, 64); if (lane >= d) x += y; }
      unsigned total = __shfl(x, 63, 64);
      if (total) {
        unsigned base = 0;
        if (lane == 63) base = atomicAdd(&ws->cand_cnt[1][t], total);
        base = __shfl(base, 63, 64);
        unsigned off = base + x - nb;
#pragma unroll
        for (int j = 0; j < 4; ++j)
          if ((mb >> j) & 1u) { if (off < CAP) candb[off] = ub[j]; off++; }
      }
    }
  }
  // block-reduce the exact below-lo counts
  for (int off = 32; off; off >>= 1) {
    cbg += __shfl_down(cbg, off);
    cbb += __shfl_down(cbb, off);
  }
  __shared__ unsigned pg[4], pb[4];
  const int wave = tx >> 6;
  if (lane == 0) { pg[wave] = cbg; pb[wave] = cbb; }
  __syncthreads();
  if (tx == 0) {
    atomicAdd(&ws->cnt_below[0][t], pg[0] + pg[1] + pg[2] + pg[3]);
    atomicAdd(&ws->cnt_below[1][t], pb[0] + pb[1] + pb[2] + pb[3]);
  }
}

// ---------------- pass 2: exact radix select among candidates ----------------
__global__ __launch_bounds__(256) void cand_select_kernel(WS* ws) {
  const int t = blockIdx.x, q = blockIdx.y;
  const unsigned* __restrict__ cand = ws->cand[q][t];
  unsigned n = ws->cand_cnt[q][t];
  if (n > CAP) n = CAP;
  const unsigned R = (q == 0) ? RANK_G : RANK_B;
  long long rk = (long long)R - (long long)ws->cnt_below[q][t];
  if (rk < 0) rk = 0;
  if (rk >= (long long)n) rk = (long long)n - 1;   // safety clamp
  unsigned rank = (unsigned)rk;

  __shared__ unsigned hist[2048];
  __shared__ unsigned partial[256], chunk_before[256], sel[2];
  const int tx = threadIdx.x;
  unsigned prefix = 0;
  for (int lvl = 0; lvl < 3; ++lvl) {
    for (int i = tx; i < 2048; i += 256) hist[i] = 0;
    __syncthreads();
    for (unsigned i = tx; i < n; i += 256) {
      unsigned u = cand[i];
      bool ok = (lvl == 0) || (lvl == 1 ? (u >> 21) == prefix : (u >> 10) == prefix);
      if (ok) {
        unsigned b = (lvl == 0) ? (u >> 21) : (lvl == 1 ? (u >> 10) & 2047u : u & 1023u);
        atomicAdd(&hist[b], 1u);
      }
    }
    __syncthreads();
    unsigned s = 0;
    for (int j = 0; j < 8; ++j) s += hist[tx * 8 + j];
    partial[tx] = s;
    __syncthreads();
    if (tx == 0) {
      unsigned cum = 0;
      for (int i = 0; i < 256; ++i) { chunk_before[i] = cum; cum += partial[i]; }
    }
    __syncthreads();
    unsigned cb = chunk_before[tx];
    if (rank >= cb && rank < cb + partial[tx]) {
      unsigned rem = rank - cb, cum = 0;
      for (int j = 0; j < 8; ++j) {
        unsigned hv = hist[tx * 8 + j];
        if (rem < cum + hv) { sel[0] = tx * 8 + j; sel[1] = rem - cum; break; }
        cum += hv;
      }
    }
    __syncthreads();
    unsigned bucket = sel[0];
    rank = sel[1];
    if (lvl == 0)      prefix = bucket;                   // == u>>21
    else if (lvl == 1) prefix = (prefix << 11) | bucket;  // == u>>10
    else if (tx == 0)  ws->thr[q][t] = __uint_as_float((prefix << 10) | bucket);
    __syncthreads();
  }
}

// ---------------- masked stats pass ----------------
__global__ __launch_bounds__(256) void stats_kernel(const float* __restrict__ frames,
                                                    WS* ws) {
  const int t  = blockIdx.y;
  const int r0 = blockIdx.x * ROWS_PER_BLOCK;
  const float thrg = ws->thr[0][t];
  const float thrb = ws->thr[1][t];
  const float* f = frames + (size_t)t * N_;
  const int tx = threadIdx.x;
  const int c  = tx * 4;

  float cnt = 0.f, sgm = 0.f, swx = 0.f, swy = 0.f;
  for (int r = 0; r < ROWS_PER_BLOCK; ++r) {
    const int h = r0 + r;
    const float* row = f + (size_t)h * W_;
    float4 a = *(const float4*)(row + c);
    float an = (c + 4 < W_) ? row[c + 4] : 0.0f;
    float4 b;
    if (h + 1 < H_) b = *(const float4*)(row + W_ + c);
    else            b = a;
    float xs[5] = {a.x, a.y, a.z, a.w, an};
    float ys[4] = {b.x, b.y, b.z, b.w};
#pragma unroll
    for (int j = 0; j < 4; ++j) {
      float gm = gm_at(xs[j], xs[j + 1], ys[j], c + j, h);
      float bz = fabsf(xs[j]);
      if (gm > thrg && bz < thrb) {
        cnt += 1.0f;
        sgm += gm;
        swx += gm * (float)(c + j);
        swy += gm * (float)h;
      }
    }
  }
  for (int off = 32; off; off >>= 1) {
    cnt += __shfl_down(cnt, off);
    sgm += __shfl_down(sgm, off);
    swx += __shfl_down(swx, off);
    swy += __shfl_down(swy, off);
  }
  __shared__ double pc[4], pg[4], px[4], py[4];
  const int wave = tx >> 6;
  if ((tx & 63) == 0) { pc[wave] = cnt; pg[wave] = sgm; px[wave] = swx; py[wave] = swy; }
  __syncthreads();
  if (tx == 0) {
    atomicAdd(&ws->acc[t][0], pc[0] + pc[1] + pc[2] + pc[3]);
    atomicAdd(&ws->acc[t][1], pg[0] + pg[1] + pg[2] + pg[3]);
    atomicAdd(&ws->acc[t][2], px[0] + px[1] + px[2] + px[3]);
    atomicAdd(&ws->acc[t][3], py[0] + py[1] + py[2] + py[3]);
  }
}

// ---------------- finalize: per-frame stats -> conv -> 8 scalars ----------------
__global__ __launch_bounds__(64) void finalize_kernel(WS* ws,
                                                      const float* __restrict__ conv_w,
                                                      const float* __restrict__ conv_b,
                                                      float* __restrict__ out) {
  __shared__ float st[T_][4];
  __shared__ float s[T_][4];
  const int tx = threadIdx.x;
  if (tx < T_) {
    double cnt = ws->acc[tx][0];
    double sgm = ws->acc[tx][1];
    double swx = ws->acc[tx][2];
    double swy = ws->acc[tx][3];
    float pil  = fmaxf((float)cnt, 1e-6f);
    float wsum = fmaxf((float)sgm, 1e-6f);
    st[tx][0] = pil / (float)N_;
    st[tx][1] = (float)sgm / pil;
    st[tx][2] = (float)swx / wsum / (float)W_;
    st[tx][3] = (float)swy / wsum / (float)H_;
  }
  __syncthreads();
  if (tx < T_) {
#pragma unroll
    for (int c2 = 0; c2 < 4; ++c2) {
      float acc = conv_b[c2];
#pragma unroll
      for (int k = 0; k < 3; ++k) {
        int ti = tx + k - 1;
        if (ti >= 0 && ti < T_) acc += conv_w[c2 * 3 + k] * st[ti][c2];
      }
      s[tx][c2] = acc;
    }
  }
  __syncthreads();
  if (tx == 0) {
    float lm = 0.f, im = 0.f;
    for (int i = 0; i < T_; ++i) { lm += s[i][0]; im += s[i][1]; }
    lm /= (float)T_; im /= (float)T_;
    float lt = 0.f, it = 0.f;
    for (int i = 0; i < T_; ++i) {
      float tn = (float)i / (float)(T_ - 1) - 0.5f;
      lt += (s[i][0] - lm) * tn;
      it += (s[i][1] - im) * tn;
    }
    lt *= 6.0f / (float)T_;
    it *= 6.0f / (float)T_;
    float speeds[T_ - 1];
    float spsum = 0.f, sdx = 0.f, sdy = 0.f;
    for (int i = 0; i < T_ - 1; ++i) {
      float dx = s[i + 1][2] - s[i][2];
      float dy = s[i + 1][3] - s[i][3];
      float sp = sqrtf(dx * dx + dy * dy);
      speeds[i] = sp; spsum += sp; sdx += dx; sdy += dy;
    }
    float ms  = spsum / (float)(T_ - 1);
    float dir = atan2f(sdy, sdx) / 3.14159265358979323846f;
    float gr  = (s[T_ - 1][0] - s[0][0]) / (float)(T_ - 1);
    float var = 0.f;
    for (int i = 0; i < T_ - 1; ++i) { float d = speeds[i] - ms; var += d * d; }
    float inst = sqrtf(var / (float)(T_ - 2));
    out[0] = lm; out[1] = lt; out[2] = im; out[3] = it;
    out[4] = ms; out[5] = dir; out[6] = gr; out[7] = inst;
  }
}

// ---------------- launch ----------------
extern "C" void kernel_launch(void* const* d_in, const int* in_sizes, int n_in,
                              void* d_out, int out_size, void* d_ws, size_t ws_size,
                              hipStream_t stream) {
  const float* frames = (const float*)d_in[0];
  const float* conv_w = (const float*)d_in[2];
  const float* conv_b = (const float*)d_in[3];
  float* out = (float*)d_out;
  WS* ws = (WS*)d_ws;

  // zero only the header (cand buffers need no init)
  hipMemsetAsync(d_ws, 0, offsetof(WS, cand), stream);

  dim3 grid(BLOCKS_PER_FRAME, T_);
  sample_kernel<<<T_, 256, 0, stream>>>(frames, ws);
  count_compact_kernel<<<grid, 256, 0, stream>>>(frames, ws);
  cand_select_kernel<<<dim3(T_, 2), 256, 0, stream>>>(ws);
  stats_kernel<<<grid, 256, 0, stream>>>(frames, ws);
  finalize_kernel<<<1, 64, 0, stream>>>(ws, conv_w, conv_b, out);
}

// Round 3
// 630.680 us; speedup vs baseline: 2.8813x; 2.8813x over previous
//
#include <hip/hip_runtime.h>
#include <math.h>
#include <stddef.h>

// ---------------- problem constants ----------------
constexpr int T_ = 64;
constexpr int H_ = 1024;
constexpr int W_ = 1024;
constexpr int N_ = H_ * W_;
// int((1.0-0.15)*(N-1)) and int(0.3*(N-1)) with python double semantics
constexpr unsigned RANK_G = 891288;   // 85th pct index of gm (ascending, 0-based)
constexpr unsigned RANK_B = 314572;   // 30th pct index of |f|

constexpr int ROWS_PER_BLOCK = 32;
constexpr int BLOCKS_PER_FRAME = H_ / ROWS_PER_BLOCK; // 32

// sampling: 16 rows/frame = 16384 samples; N/NS = 64
constexpr int SROWS = 16;
constexpr int NS = SROWS * W_;              // 16384
constexpr int SHB = 8192;                   // stage-1 buckets (u>>18)
constexpr int MARGIN = 192;                 // sample-rank margin (~4.4 sigma in pop rank)
constexpr int RS_G = (int)(RANK_G / 64);    // 13926
constexpr int RS_B = (int)(RANK_B / 64);    // 4915

// per-block segment capacities (expected ~770 / ~770 / ~125)
constexpr unsigned CAPG = 1536;
constexpr unsigned CAPB = 1536;
constexpr unsigned CAPX = 448;

// ---------------- workspace layout (~48.9 MB) ----------------
struct WS {
  unsigned lo[2][T_], hi[2][T_];       // refined value brackets (bit patterns)
  unsigned cntG[T_][32], cntB[T_][32], cntX[T_][32];
  unsigned cbG[T_][32], cbB[T_][32];   // per-block #{u < lo}
  float    thr[2][T_];
  double   part[T_][32][4];            // per-block certain-true partial stats
  double   acc[T_][4];                 // final per-frame cnt, sum_gm, sum_gm*x, sum_gm*y
  unsigned Gg[T_][32][CAPG];           // gm bracket candidates: gm bits
  unsigned Ga[T_][32][CAPG];           //   aux: x|y<<10|certain_bz_flag<<20
  unsigned Bb[T_][32][CAPB];           // bz bracket candidates: bz bits
  unsigned Xg[T_][32][CAPX];           // uncertain-stats records (bz in bracket, gm >= lo_g)
  unsigned Xb[T_][32][CAPX];
  unsigned Xa[T_][32][CAPX];           //   aux: x|y<<10
};

// Shared gm computation so every pass rounds identically.
__device__ __forceinline__ float gm_at(float cur, float right, float down,
                                       int col, int row) {
  float gx = (col < W_ - 1) ? (right - cur) : 0.0f;
  float gy = (row < H_ - 1) ? (down - cur) : 0.0f;
  return sqrtf(gx * gx + gy * gy);
}

// ---------------- pass 0: sampled bracket estimation (2-stage refine) ----------
__global__ __launch_bounds__(256) void sample_kernel(const float* __restrict__ frames,
                                                     WS* ws) {
  const int t = blockIdx.x;
  __shared__ unsigned hist[2][SHB];        // 64 KB
  __shared__ unsigned sub[4][1024];        // 16 KB, (q*2+e)
  __shared__ unsigned partial[256], chunk_before[256];
  __shared__ unsigned selB[4], selCB[4];
  const int tx = threadIdx.x, c = tx * 4;
  for (int i = tx; i < 2 * SHB; i += 256) (&hist[0][0])[i] = 0;
  for (int i = tx; i < 4 * 1024; i += 256) (&sub[0][0])[i] = 0;
  __syncthreads();
  const float* f = frames + (size_t)t * N_;

  // stage-1 histogram over 16 sampled rows
  for (int r = 0; r < SROWS; ++r) {
    const int h = r * 64 + 32;                 // 32..992, h+1 always valid
    const float* row = f + (size_t)h * W_;
    float4 a = *(const float4*)(row + c);
    float an = (c + 4 < W_) ? row[c + 4] : 0.0f;
    float4 b = *(const float4*)(row + W_ + c);
    float xs[5] = {a.x, a.y, a.z, a.w, an};
    float ys[4] = {b.x, b.y, b.z, b.w};
#pragma unroll
    for (int j = 0; j < 4; ++j) {
      float gm = gm_at(xs[j], xs[j + 1], ys[j], c + j, h);
      float bz = fabsf(xs[j]);
      atomicAdd(&hist[0][__float_as_uint(gm) >> 18], 1u);
      atomicAdd(&hist[1][__float_as_uint(bz) >> 18], 1u);
    }
  }
  __syncthreads();

  // stage-1 select: bucket + count-below-bucket for each (q, endpoint)
  for (int q = 0; q < 2; ++q) {
    unsigned s = 0;
    for (int j = 0; j < SHB / 256; ++j) s += hist[q][tx * (SHB / 256) + j];
    partial[tx] = s;
    __syncthreads();
    if (tx == 0) {
      unsigned cum = 0;
      for (int i = 0; i < 256; ++i) { chunk_before[i] = cum; cum += partial[i]; }
    }
    __syncthreads();
    for (int e = 0; e < 2; ++e) {
      int k = (q == 0 ? RS_G : RS_B) + (e == 0 ? -MARGIN : MARGIN);
      unsigned cb = chunk_before[tx];
      if ((unsigned)k >= cb && (unsigned)k < cb + partial[tx]) {
        unsigned rem = (unsigned)k - cb, cum = 0;
        for (int j = 0; j < SHB / 256; ++j) {
          unsigned hv = hist[q][tx * (SHB / 256) + j];
          if (rem < cum + hv) {
            selB[q * 2 + e]  = tx * (SHB / 256) + j;
            selCB[q * 2 + e] = cb + cum;
            break;
          }
          cum += hv;
        }
      }
    }
    __syncthreads();
  }

  // stage-2 histogram: re-read samples, refine within selected buckets
  for (int r = 0; r < SROWS; ++r) {
    const int h = r * 64 + 32;
    const float* row = f + (size_t)h * W_;
    float4 a = *(const float4*)(row + c);
    float an = (c + 4 < W_) ? row[c + 4] : 0.0f;
    float4 b = *(const float4*)(row + W_ + c);
    float xs[5] = {a.x, a.y, a.z, a.w, an};
    float ys[4] = {b.x, b.y, b.z, b.w};
#pragma unroll
    for (int j = 0; j < 4; ++j) {
      float gm = gm_at(xs[j], xs[j + 1], ys[j], c + j, h);
      float bz = fabsf(xs[j]);
      unsigned ug = __float_as_uint(gm), ub = __float_as_uint(bz);
#pragma unroll
      for (int e = 0; e < 2; ++e) {
        if ((ug >> 18) == selB[e])     atomicAdd(&sub[e][(ug >> 8) & 1023u], 1u);
        if ((ub >> 18) == selB[2 + e]) atomicAdd(&sub[2 + e][(ub >> 8) & 1023u], 1u);
      }
    }
  }
  __syncthreads();

  // stage-2 select per (q,e) -> refined bound at 2^8 bit granularity
  for (int qe = 0; qe < 4; ++qe) {
    unsigned s = 0;
    for (int j = 0; j < 4; ++j) s += sub[qe][tx * 4 + j];
    partial[tx] = s;
    __syncthreads();
    if (tx == 0) {
      unsigned cum = 0;
      for (int i = 0; i < 256; ++i) { chunk_before[i] = cum; cum += partial[i]; }
    }
    __syncthreads();
    int q = qe >> 1, e = qe & 1;
    int k0 = (q == 0 ? RS_G : RS_B) + (e == 0 ? -MARGIN : MARGIN);
    unsigned k = (unsigned)k0 - selCB[qe];      // rank within bucket
    unsigned cb = chunk_before[tx];
    if (k >= cb && k < cb + partial[tx]) {
      unsigned rem = k - cb, cum = 0;
      for (int j = 0; j < 4; ++j) {
        unsigned hv = sub[qe][tx * 4 + j];
        if (rem < cum + hv) {
          unsigned sb = tx * 4 + j;
          unsigned bound = (selB[qe] << 18) | (sb << 8);
          if (e == 0) ws->lo[q][t] = bound;
          else        ws->hi[q][t] = bound + 256u;
          break;
        }
        cum += hv;
      }
    }
    __syncthreads();
  }
}

// ---------------- pass 1: the ONLY full streaming pass ----------------
__global__ __launch_bounds__(256) void main_kernel(const float* __restrict__ frames,
                                                   WS* ws) {
  const int t = blockIdx.y, blk = blockIdx.x, r0 = blk * ROWS_PER_BLOCK;
  const unsigned lg = ws->lo[0][t], hg = ws->hi[0][t];
  const unsigned lb = ws->lo[1][t], hb = ws->hi[1][t];
  __shared__ unsigned cnt[3];
  const int tx = threadIdx.x, c = tx * 4, lane = tx & 63, wave = tx >> 6;
  if (tx < 3) cnt[tx] = 0;
  __syncthreads();
  unsigned* __restrict__ Gg = ws->Gg[t][blk];
  unsigned* __restrict__ Ga = ws->Ga[t][blk];
  unsigned* __restrict__ Bb = ws->Bb[t][blk];
  unsigned* __restrict__ Xg = ws->Xg[t][blk];
  unsigned* __restrict__ Xb = ws->Xb[t][blk];
  unsigned* __restrict__ Xa = ws->Xa[t][blk];
  const float* f = frames + (size_t)t * N_;

  unsigned cbg = 0, cbb = 0;
  float s0 = 0.f, s1 = 0.f, s2 = 0.f, s3 = 0.f;

  for (int r = 0; r < ROWS_PER_BLOCK; ++r) {
    const int h = r0 + r;
    const float* row = f + (size_t)h * W_;
    float4 a = *(const float4*)(row + c);
    float an = (c + 4 < W_) ? row[c + 4] : 0.0f;
    float4 b;
    if (h + 1 < H_) b = *(const float4*)(row + W_ + c);
    else            b = a;                     // forces gy = 0
    float xs[5] = {a.x, a.y, a.z, a.w, an};
    float ys[4] = {b.x, b.y, b.z, b.w};
#pragma unroll
    for (int j = 0; j < 4; ++j) {
      float gm = gm_at(xs[j], xs[j + 1], ys[j], c + j, h);
      float bz = fabsf(xs[j]);
      unsigned ug = __float_as_uint(gm);
      unsigned ub = __float_as_uint(bz);
      bool bz_lo = (ub < lb);
      if (ug < lg) {
        cbg++;
      } else if (ug < hg) {                    // gm bracket candidate
        unsigned o = atomicAdd(&cnt[0], 1u);
        if (o < CAPG) {
          Gg[o] = ug;
          Ga[o] = (unsigned)(c + j) | ((unsigned)h << 10) | (bz_lo ? (1u << 20) : 0u);
        }
      }
      if (bz_lo) {
        cbb++;
        if (ug >= hg) {                        // certainly in mask
          s0 += 1.0f; s1 += gm;
          s2 += gm * (float)(c + j); s3 += gm * (float)h;
        }
      } else if (ub < hb) {                    // bz bracket candidate
        unsigned o = atomicAdd(&cnt[1], 1u);
        if (o < CAPB) Bb[o] = ub;
        if (ug >= lg) {                        // stats outcome uncertain
          unsigned o2 = atomicAdd(&cnt[2], 1u);
          if (o2 < CAPX) {
            Xg[o2] = ug; Xb[o2] = ub;
            Xa[o2] = (unsigned)(c + j) | ((unsigned)h << 10);
          }
        }
      }
    }
  }

  // block-reduce partials (no global atomics anywhere)
  for (int off = 32; off; off >>= 1) {
    cbg += __shfl_down(cbg, off);
    cbb += __shfl_down(cbb, off);
    s0  += __shfl_down(s0, off);
    s1  += __shfl_down(s1, off);
    s2  += __shfl_down(s2, off);
    s3  += __shfl_down(s3, off);
  }
  __shared__ unsigned wcb[2][4];
  __shared__ float wss[4][4];
  if (lane == 0) {
    wcb[0][wave] = cbg; wcb[1][wave] = cbb;
    wss[0][wave] = s0; wss[1][wave] = s1; wss[2][wave] = s2; wss[3][wave] = s3;
  }
  __syncthreads();
  if (tx == 0) {
    ws->cbG[t][blk] = wcb[0][0] + wcb[0][1] + wcb[0][2] + wcb[0][3];
    ws->cbB[t][blk] = wcb[1][0] + wcb[1][1] + wcb[1][2] + wcb[1][3];
    ws->part[t][blk][0] = (double)wss[0][0] + wss[0][1] + wss[0][2] + wss[0][3];
    ws->part[t][blk][1] = (double)wss[1][0] + wss[1][1] + wss[1][2] + wss[1][3];
    ws->part[t][blk][2] = (double)wss[2][0] + wss[2][1] + wss[2][2] + wss[2][3];
    ws->part[t][blk][3] = (double)wss[3][0] + wss[3][1] + wss[3][2] + wss[3][3];
    ws->cntG[t][blk] = min(cnt[0], CAPG);
    ws->cntB[t][blk] = min(cnt[1], CAPB);
    ws->cntX[t][blk] = min(cnt[2], CAPX);
  }
}

// ---------------- pass 2: exact radix select over bracket candidates ----------
__global__ __launch_bounds__(256) void select_kernel(WS* ws) {
  const int t = blockIdx.x, q = blockIdx.y, tx = threadIdx.x;
  __shared__ unsigned hist[2048], partial[256], chunk_before[256], sel[2];
  __shared__ unsigned nseg[32];
  __shared__ unsigned shrank;
  const unsigned lo = ws->lo[q][t];
  if (tx < 32) nseg[tx] = (q == 0) ? ws->cntG[t][tx] : ws->cntB[t][tx];
  __syncthreads();
  if (tx == 0) {
    unsigned cb = 0, total = 0;
    for (int i = 0; i < 32; ++i) {
      cb += (q == 0) ? ws->cbG[t][i] : ws->cbB[t][i];
      total += nseg[i];
    }
    long long rk = (long long)((q == 0) ? RANK_G : RANK_B) - (long long)cb;
    if (rk < 0) rk = 0;
    if (total > 0 && rk >= (long long)total) rk = (long long)total - 1;
    shrank = (unsigned)rk;
  }
  __syncthreads();
  unsigned rank = shrank, prefix = 0;
  for (int lvl = 0; lvl < 3; ++lvl) {
    for (int i = tx; i < 2048; i += 256) hist[i] = 0;
    __syncthreads();
    for (int blk = 0; blk < 32; ++blk) {
      const unsigned n = nseg[blk];
      const unsigned* __restrict__ ptr = (q == 0) ? ws->Gg[t][blk] : ws->Bb[t][blk];
      for (unsigned i = tx; i < n; i += 256) {
        unsigned d = ptr[i] - lo;        // all candidates >= lo
        if (lvl == 0) atomicAdd(&hist[d >> 21], 1u);
        else if (lvl == 1) { if ((d >> 21) == prefix) atomicAdd(&hist[(d >> 10) & 2047u], 1u); }
        else               { if ((d >> 10) == prefix) atomicAdd(&hist[d & 1023u], 1u); }
      }
    }
    __syncthreads();
    unsigned s = 0;
    for (int j = 0; j < 8; ++j) s += hist[tx * 8 + j];
    partial[tx] = s;
    __syncthreads();
    if (tx == 0) {
      unsigned cum = 0;
      for (int i = 0; i < 256; ++i) { chunk_before[i] = cum; cum += partial[i]; }
    }
    __syncthreads();
    unsigned cb2 = chunk_before[tx];
    if (rank >= cb2 && rank < cb2 + partial[tx]) {
      unsigned rem = rank - cb2, cum = 0;
      for (int j = 0; j < 8; ++j) {
        unsigned hv = hist[tx * 8 + j];
        if (rem < cum + hv) { sel[0] = tx * 8 + j; sel[1] = rem - cum; break; }
        cum += hv;
      }
    }
    __syncthreads();
    rank = sel[1];
    if (lvl == 0)      prefix = sel[0];
    else if (lvl == 1) prefix = (prefix << 11) | sel[0];
    else if (tx == 0)  ws->thr[q][t] = __uint_as_float(lo + ((prefix << 10) | sel[0]));
    __syncthreads();
  }
}

// ---------------- pass 3: resolve uncertain records against exact thresholds --
__global__ __launch_bounds__(256) void resolve_kernel(WS* ws) {
  const int t = blockIdx.x, tx = threadIdx.x;
  const unsigned tg = __float_as_uint(ws->thr[0][t]);
  const unsigned tb = __float_as_uint(ws->thr[1][t]);
  float c = 0.f, sg = 0.f, sx = 0.f, sy = 0.f;
  for (int blk = 0; blk < 32; ++blk) {
    const unsigned nG = ws->cntG[t][blk];
    const unsigned* __restrict__ Gg = ws->Gg[t][blk];
    const unsigned* __restrict__ Ga = ws->Ga[t][blk];
    for (unsigned i = tx; i < nG; i += 256) {
      unsigned g = Gg[i], a = Ga[i];
      if (g > tg && (a & (1u << 20))) {
        float v = __uint_as_float(g);
        c += 1.f; sg += v;
        sx += v * (float)(a & 1023u);
        sy += v * (float)((a >> 10) & 1023u);
      }
    }
    const unsigned nX = ws->cntX[t][blk];
    const unsigned* __restrict__ Xg = ws->Xg[t][blk];
    const unsigned* __restrict__ Xb = ws->Xb[t][blk];
    const unsigned* __restrict__ Xa = ws->Xa[t][blk];
    for (unsigned i = tx; i < nX; i += 256) {
      unsigned g = Xg[i], bb = Xb[i], a = Xa[i];
      if (g > tg && bb < tb) {
        float v = __uint_as_float(g);
        c += 1.f; sg += v;
        sx += v * (float)(a & 1023u);
        sy += v * (float)((a >> 10) & 1023u);
      }
    }
  }
  double dc = c, dg = sg, dx = sx, dy = sy;
  if (tx < 32) {
    dc += ws->part[t][tx][0];
    dg += ws->part[t][tx][1];
    dx += ws->part[t][tx][2];
    dy += ws->part[t][tx][3];
  }
  for (int off = 32; off; off >>= 1) {
    dc += __shfl_down(dc, off);
    dg += __shfl_down(dg, off);
    dx += __shfl_down(dx, off);
    dy += __shfl_down(dy, off);
  }
  __shared__ double pd[4][4];
  const int wave = tx >> 6, lane = tx & 63;
  if (lane == 0) { pd[0][wave] = dc; pd[1][wave] = dg; pd[2][wave] = dx; pd[3][wave] = dy; }
  __syncthreads();
  if (tx == 0) {
    ws->acc[t][0] = pd[0][0] + pd[0][1] + pd[0][2] + pd[0][3];
    ws->acc[t][1] = pd[1][0] + pd[1][1] + pd[1][2] + pd[1][3];
    ws->acc[t][2] = pd[2][0] + pd[2][1] + pd[2][2] + pd[2][3];
    ws->acc[t][3] = pd[3][0] + pd[3][1] + pd[3][2] + pd[3][3];
  }
}

// ---------------- finalize: per-frame stats -> conv -> 8 scalars ----------------
__global__ __launch_bounds__(64) void finalize_kernel(WS* ws,
                                                      const float* __restrict__ conv_w,
                                                      const float* __restrict__ conv_b,
                                                      float* __restrict__ out) {
  __shared__ float st[T_][4];
  __shared__ float s[T_][4];
  const int tx = threadIdx.x;
  if (tx < T_) {
    double cnt = ws->acc[tx][0];
    double sgm = ws->acc[tx][1];
    double swx = ws->acc[tx][2];
    double swy = ws->acc[tx][3];
    float pil  = fmaxf((float)cnt, 1e-6f);
    float wsum = fmaxf((float)sgm, 1e-6f);
    st[tx][0] = pil / (float)N_;
    st[tx][1] = (float)sgm / pil;
    st[tx][2] = (float)swx / wsum / (float)W_;
    st[tx][3] = (float)swy / wsum / (float)H_;
  }
  __syncthreads();
  if (tx < T_) {
#pragma unroll
    for (int c2 = 0; c2 < 4; ++c2) {
      float acc = conv_b[c2];
#pragma unroll
      for (int k = 0; k < 3; ++k) {
        int ti = tx + k - 1;
        if (ti >= 0 && ti < T_) acc += conv_w[c2 * 3 + k] * st[ti][c2];
      }
      s[tx][c2] = acc;
    }
  }
  __syncthreads();
  if (tx == 0) {
    float lm = 0.f, im = 0.f;
    for (int i = 0; i < T_; ++i) { lm += s[i][0]; im += s[i][1]; }
    lm /= (float)T_; im /= (float)T_;
    float lt = 0.f, it = 0.f;
    for (int i = 0; i < T_; ++i) {
      float tn = (float)i / (float)(T_ - 1) - 0.5f;
      lt += (s[i][0] - lm) * tn;
      it += (s[i][1] - im) * tn;
    }
    lt *= 6.0f / (float)T_;
    it *= 6.0f / (float)T_;
    float speeds[T_ - 1];
    float spsum = 0.f, sdx = 0.f, sdy = 0.f;
    for (int i = 0; i < T_ - 1; ++i) {
      float dx = s[i + 1][2] - s[i][2];
      float dy = s[i + 1][3] - s[i][3];
      float sp = sqrtf(dx * dx + dy * dy);
      speeds[i] = sp; spsum += sp; sdx += dx; sdy += dy;
    }
    float ms  = spsum / (float)(T_ - 1);
    float dir = atan2f(sdy, sdx) / 3.14159265358979323846f;
    float gr  = (s[T_ - 1][0] - s[0][0]) / (float)(T_ - 1);
    float var = 0.f;
    for (int i = 0; i < T_ - 1; ++i) { float d = speeds[i] - ms; var += d * d; }
    float inst = sqrtf(var / (float)(T_ - 2));
    out[0] = lm; out[1] = lt; out[2] = im; out[3] = it;
    out[4] = ms; out[5] = dir; out[6] = gr; out[7] = inst;
  }
}

// ---------------- launch ----------------
extern "C" void kernel_launch(void* const* d_in, const int* in_sizes, int n_in,
                              void* d_out, int out_size, void* d_ws, size_t ws_size,
                              hipStream_t stream) {
  const float* frames = (const float*)d_in[0];
  const float* conv_w = (const float*)d_in[2];
  const float* conv_b = (const float*)d_in[3];
  float* out = (float*)d_out;
  WS* ws = (WS*)d_ws;

  // no memset needed: every WS field consumed is written unconditionally first

  sample_kernel<<<T_, 256, 0, stream>>>(frames, ws);
  main_kernel<<<dim3(BLOCKS_PER_FRAME, T_), 256, 0, stream>>>(frames, ws);
  select_kernel<<<dim3(T_, 2), 256, 0, stream>>>(ws);
  resolve_kernel<<<T_, 256, 0, stream>>>(ws);
  finalize_kernel<<<1, 64, 0, stream>>>(ws, conv_w, conv_b, out);
}